// Round 4
// baseline (278.614 us; speedup 1.0000x reference)
//
#include <hip/hip_runtime.h>
#include <hip/hip_bf16.h>

#define NN 8192
#define LOG2E 1.44269504088896f

typedef __attribute__((ext_vector_type(8))) short short8;
typedef __attribute__((ext_vector_type(4))) float f32x4;

static __device__ __forceinline__ float bf2f(unsigned short u) {
    union { unsigned int i; float f; } v; v.i = ((unsigned int)u) << 16; return v.f;
}
static __device__ __forceinline__ unsigned short f2bf(float f) {
    union { float f; unsigned int i; } v; v.f = f;
    unsigned int lsb = (v.i >> 16) & 1u;
    v.i += 0x7fffu + lsb;
    return (unsigned short)(v.i >> 16);
}
// pack 2 f32 -> 2 bf16 in one u32 (RTNE), single HW op
static __device__ __forceinline__ unsigned int cvtpk(float lo, float hi) {
    unsigned int r;
    asm("v_cvt_pk_bf16_f32 %0, %1, %2" : "=v"(r) : "v"(lo), "v"(hi));
    return r;
}
static __device__ __forceinline__ float fexp2(float x) { return __builtin_amdgcn_exp2f(x); }

// Convert 8 contiguous f32 to bf16 hi + bf16 residual lo (for split-MFMA).
static __device__ __forceinline__ void cvt8(const float* __restrict__ p, short8& hi, short8& lo) {
    float4 u = *(const float4*)p;
    float4 v = *(const float4*)(p + 4);
    float f[8] = {u.x, u.y, u.z, u.w, v.x, v.y, v.z, v.w};
#pragma unroll
    for (int j = 0; j < 8; ++j) {
        unsigned short hb = f2bf(f[j]);
        hi[j] = (short)hb;
        lo[j] = (short)f2bf(f[j] - bf2f(hb));
    }
}

// ---- prep: v1/v2 (W^T a vectors), split over 16 blocks then reduced ----
__global__ void prep_partial(const float* __restrict__ W1, const float* __restrict__ W2,
                             const float* __restrict__ a,
                             float* __restrict__ v1p, float* __restrict__ v2p) {
    int b = blockIdx.x;            // 0..15
    int t = threadIdx.x;           // 512: (hh, k)
    int hh = t >> 8, k = t & 255;
    int c0 = (b & 7) * 16;
    const float* W = (b < 8) ? W1 : W2;
    int aoff = (b < 8) ? 0 : 128;
    float acc = 0.f;
    for (int c = c0; c < c0 + 16; ++c)
        acc += W[(size_t)(hh * 128 + c) * 256 + k] * a[hh * 256 + aoff + c];
    ((b < 8) ? v1p : v2p)[(b & 7) * 512 + t] = acc;
}

__global__ void prep_reduce(const float* __restrict__ b1, const float* __restrict__ b2,
                            const float* __restrict__ a,
                            const float* __restrict__ v1p, const float* __restrict__ v2p,
                            float* __restrict__ v1, float* __restrict__ v2, float* __restrict__ bd) {
    int t = threadIdx.x;           // 512
    float a1 = 0.f, a2 = 0.f;
    for (int b = 0; b < 8; ++b) { a1 += v1p[b * 512 + t]; a2 += v2p[b * 512 + t]; }
    v1[t] = a1;
    v2[t] = a2;
    if (t < 4) {
        int hh = t >> 1, which = t & 1;
        float d = 0.f;
        for (int c = 0; c < 128; ++c)
            d += which ? b2[hh * 128 + c] * a[hh * 256 + 128 + c]
                       : b1[hh * 128 + c] * a[hh * 256 + c];
        bd[hh * 2 + which] = d;
    }
}

// s1[n][h], s2[n][h] f32, interleaved pairs, PRE-SCALED by log2(e) for exp2-domain P-gen.
__global__ __launch_bounds__(256) void s_kernel(const float* __restrict__ hmat,
                         const float* __restrict__ v1, const float* __restrict__ v2,
                         const float* __restrict__ bd,
                         float* __restrict__ s1o, float* __restrict__ s2o) {
    int w = threadIdx.x >> 6, l = threadIdx.x & 63;
    int n = blockIdx.x * 4 + w;
    float4 hv  = *(const float4*)(hmat + (size_t)n * 256 + l * 4);
    float4 va0 = *(const float4*)(v1 + l * 4);
    float4 va1 = *(const float4*)(v1 + 256 + l * 4);
    float4 vb0 = *(const float4*)(v2 + l * 4);
    float4 vb1 = *(const float4*)(v2 + 256 + l * 4);
    float s10 = hv.x*va0.x + hv.y*va0.y + hv.z*va0.z + hv.w*va0.w;
    float s11 = hv.x*va1.x + hv.y*va1.y + hv.z*va1.z + hv.w*va1.w;
    float s20 = hv.x*vb0.x + hv.y*vb0.y + hv.z*vb0.z + hv.w*vb0.w;
    float s21 = hv.x*vb1.x + hv.y*vb1.y + hv.z*vb1.z + hv.w*vb1.w;
#pragma unroll
    for (int off = 1; off < 64; off <<= 1) {
        s10 += __shfl_xor(s10, off);
        s11 += __shfl_xor(s11, off);
        s20 += __shfl_xor(s20, off);
        s21 += __shfl_xor(s21, off);
    }
    if (l == 0) {
        s1o[n*2 + 0] = (s10 + bd[0]) * LOG2E;
        s1o[n*2 + 1] = (s11 + bd[2]) * LOG2E;
        s2o[n*2 + 0] = (s20 + bd[1]) * LOG2E;
        s2o[n*2 + 1] = (s21 + bd[3]) * LOG2E;
    }
}

// W3hT[c][n] bf16, split-bf16 3-MFMA for ~f32 accuracy. 256 blocks x 128 thr (2 waves x 16 rows).
__global__ __launch_bounds__(128) void w3_kernel(const float* __restrict__ hmat,
                                                 const float* __restrict__ W3,
                                                 const float* __restrict__ b3,
                                                 unsigned short* __restrict__ w3t) {
    int tid = threadIdx.x;
    int w = tid >> 6, l = tid & 63;
    int m = l & 15, kq = l >> 4;
    int n0 = blockIdx.x * 32 + w * 16;
    f32x4 acc[16];
#pragma unroll
    for (int ct = 0; ct < 16; ++ct) acc[ct] = (f32x4){0.f, 0.f, 0.f, 0.f};
    for (int k0 = 0; k0 < 256; k0 += 32) {
        short8 ahi, alo;
        cvt8(hmat + (size_t)(n0 + m) * 256 + k0 + kq * 8, ahi, alo);
#pragma unroll
        for (int ct = 0; ct < 16; ++ct) {
            short8 bhi, blo;
            cvt8(W3 + (size_t)(ct * 16 + m) * 256 + k0 + kq * 8, bhi, blo);
            acc[ct] = __builtin_amdgcn_mfma_f32_16x16x32_bf16(ahi, bhi, acc[ct], 0, 0, 0);
            acc[ct] = __builtin_amdgcn_mfma_f32_16x16x32_bf16(alo, bhi, acc[ct], 0, 0, 0);
            acc[ct] = __builtin_amdgcn_mfma_f32_16x16x32_bf16(ahi, blo, acc[ct], 0, 0, 0);
        }
    }
#pragma unroll
    for (int ct = 0; ct < 16; ++ct) {
        int c = ct * 16 + m;
        float bias = b3[c];
#pragma unroll
        for (int r = 0; r < 4; ++r) {
            int nn = n0 + kq * 4 + r;
            w3t[(size_t)c * NN + nn] = f2bf(acc[ct][r] + bias);
        }
    }
}

// ---- main fused attention ----
// 4 waves x 32 rows = 128 rows, 256 cols. grid = (64, S). Counted-vmcnt 2-buffer pipeline:
// per iter: [stage t+1 -> NXT][P-gen t][adj t+2 -> cur regs][MFMA over CUR][vmcnt(4)][s_barrier].
// vmcnt(4) forces stage[t+1] complete before the barrier publishes it; only adj[t+2] (4 loads)
// crosses the barrier in flight. Swizzle: slot = g ^ ((c>>1)&3) on the GLOBAL source (LDS dest
// linear, m173); read at kq ^ ((cc>>1)&3) -> every 8-lane group covers all 8 bank-groups.
__global__ __launch_bounds__(256) void attn_main(
        const int* __restrict__ adj, const float* __restrict__ s1a,
        const float* __restrict__ s2a, const unsigned short* __restrict__ w3t,
        unsigned short* __restrict__ pacc, float* __restrict__ pden, int jc)
{
    __shared__ uint4 btq[2][1024];   // 2 x 16 KB B-tile
    __shared__ float s2t[2048];      // s2 chunk (jc<=1024)

    const int tid = threadIdx.x;
    const int w = tid >> 6, l = tid & 63;
    const int m = l & 15, kq = l >> 4;
    const int i0 = blockIdx.x * 128 + w * 32;
    const int sidx = blockIdx.y;
    const int j0 = sidx * jc;
    const int nt = jc >> 5;
    const int ia = i0 + m, ib = i0 + 16 + m;
    const float s1a0 = s1a[ia*2 + 0], s1a1 = s1a[ia*2 + 1];
    const float s1b0 = s1a[ib*2 + 0], s1b1 = s1a[ib*2 + 1];
    const int* adjA = adj + (size_t)ia * NN + j0 + kq * 8;
    const int* adjB = adj + (size_t)ib * NN + j0 + kq * 8;

    auto stageB = [&](int bsel, int jcol) {
#pragma unroll
        for (int it = 0; it < 4; ++it) {
            int t = tid + it * 256;              // 0..1023 granules
            int c = t >> 2, g = t & 3;
            const unsigned short* src = w3t + (size_t)c * NN + jcol + ((g ^ ((c >> 1) & 3)) << 3);
            __builtin_amdgcn_global_load_lds(
                (const __attribute__((address_space(1))) void*)src,
                (__attribute__((address_space(3))) void*)((char*)&btq[bsel][0] + t * 16),
                16, 0, 0);
        }
    };

    f32x4 acc[2][16];
#pragma unroll
    for (int rt = 0; rt < 2; ++rt)
#pragma unroll
        for (int ct = 0; ct < 16; ++ct) acc[rt][ct] = (f32x4){0.f, 0.f, 0.f, 0.f};
    float dsa0 = 0.f, dsa1 = 0.f, dsb0 = 0.f, dsb1 = 0.f;

    // prologue: s2 chunk -> LDS, publish; then stage tile 0 + adj slots 0,1
    for (int x = tid; x < jc * 2; x += 256) s2t[x] = s2a[j0 * 2 + x];
    __syncthreads();                     // publish s2t; full drain (once)
    stageB(0, j0);
    int4 a0A0 = *(const int4*)(adjA + 0),  a0A1 = *(const int4*)(adjA + 4);
    int4 a0B0 = *(const int4*)(adjB + 0),  a0B1 = *(const int4*)(adjB + 4);
    int4 a1A0 = *(const int4*)(adjA + 32), a1A1 = *(const int4*)(adjA + 36);
    int4 a1B0 = *(const int4*)(adjB + 32), a1B1 = *(const int4*)(adjB + 36);
    asm volatile("s_waitcnt vmcnt(4)" ::: "memory");   // force stage0 + adj slot0; slot1 in flight
    __builtin_amdgcn_sched_barrier(0);
    __builtin_amdgcn_s_barrier();
    asm volatile("" ::: "memory");

    auto iter = [&](int t, int CUR, int NXT,
                    int4& rA0, int4& rA1, int4& rB0, int4& rB1) {
        const int jt = t * 32;
        // issue stage for tile t+1 (in-flight across P-gen + MFMA)
        stageB(NXT, j0 + (((t + 1) < nt ? (t + 1) : (nt - 1)) << 5));
        // P-gen for tile t from register adj + LDS s2
        int aj[8] = {rA0.x, rA0.y, rA0.z, rA0.w, rA1.x, rA1.y, rA1.z, rA1.w};
        int bj[8] = {rB0.x, rB0.y, rB0.z, rB0.w, rB1.x, rB1.y, rB1.z, rB1.w};
        union { short8 v; unsigned int u[4]; } Ua0, Ua1, Ub0, Ub1;
#pragma unroll
        for (int q = 0; q < 4; ++q) {
            float4 sv = *(const float4*)&s2t[2 * (jt + kq * 8) + 4 * q];
            float t0, t1, p0, p1;
            t0 = s1a0 + sv.x; t0 = fmaxf(t0, 0.2f * t0);
            t1 = s1a0 + sv.z; t1 = fmaxf(t1, 0.2f * t1);
            p0 = aj[2*q]   ? fexp2(t0) : 0.f;
            p1 = aj[2*q+1] ? fexp2(t1) : 0.f;
            Ua0.u[q] = cvtpk(p0, p1); dsa0 += p0 + p1;
            t0 = s1a1 + sv.y; t0 = fmaxf(t0, 0.2f * t0);
            t1 = s1a1 + sv.w; t1 = fmaxf(t1, 0.2f * t1);
            p0 = aj[2*q]   ? fexp2(t0) : 0.f;
            p1 = aj[2*q+1] ? fexp2(t1) : 0.f;
            Ua1.u[q] = cvtpk(p0, p1); dsa1 += p0 + p1;
            t0 = s1b0 + sv.x; t0 = fmaxf(t0, 0.2f * t0);
            t1 = s1b0 + sv.z; t1 = fmaxf(t1, 0.2f * t1);
            p0 = bj[2*q]   ? fexp2(t0) : 0.f;
            p1 = bj[2*q+1] ? fexp2(t1) : 0.f;
            Ub0.u[q] = cvtpk(p0, p1); dsb0 += p0 + p1;
            t0 = s1b1 + sv.y; t0 = fmaxf(t0, 0.2f * t0);
            t1 = s1b1 + sv.w; t1 = fmaxf(t1, 0.2f * t1);
            p0 = bj[2*q]   ? fexp2(t0) : 0.f;
            p1 = bj[2*q+1] ? fexp2(t1) : 0.f;
            Ub1.u[q] = cvtpk(p0, p1); dsb1 += p0 + p1;
        }
        // adj prefetch for tile t+2 into the just-consumed slot (depth 2)
        {
            int off = (((t + 2) < nt ? (t + 2) : (nt - 1)) << 5);
            rA0 = *(const int4*)(adjA + off); rA1 = *(const int4*)(adjA + off + 4);
            rB0 = *(const int4*)(adjB + off); rB1 = *(const int4*)(adjB + off + 4);
        }
        // MFMA over tile t (published by previous iter's vmcnt+barrier)
#pragma unroll
        for (int ct = 0; ct < 16; ++ct) {
            int cc = ct * 16 + m;
            short8 bfrag = *(const short8*)((const char*)&btq[CUR][0] + cc * 64 + ((kq ^ ((cc >> 1) & 3)) << 4));
            acc[0][ct] = __builtin_amdgcn_mfma_f32_16x16x32_bf16(ct < 8 ? Ua0.v : Ua1.v, bfrag, acc[0][ct], 0, 0, 0);
            acc[1][ct] = __builtin_amdgcn_mfma_f32_16x16x32_bf16(ct < 8 ? Ub0.v : Ub1.v, bfrag, acc[1][ct], 0, 0, 0);
        }
        asm volatile("s_waitcnt vmcnt(4)" ::: "memory");   // stage[t+1] landed; adj[t+2] stays in flight
        __builtin_amdgcn_sched_barrier(0);
        __builtin_amdgcn_s_barrier();
        asm volatile("" ::: "memory");
    };

    for (int t = 0; t < nt; t += 2) {
        iter(t,     0, 1, a0A0, a0A1, a0B0, a0B1);
        iter(t + 1, 1, 0, a1A0, a1A1, a1B0, a1B1);
    }

    dsa0 += __shfl_xor(dsa0, 16); dsa0 += __shfl_xor(dsa0, 32);
    dsa1 += __shfl_xor(dsa1, 16); dsa1 += __shfl_xor(dsa1, 32);
    dsb0 += __shfl_xor(dsb0, 16); dsb0 += __shfl_xor(dsb0, 32);
    dsb1 += __shfl_xor(dsb1, 16); dsb1 += __shfl_xor(dsb1, 32);
    if (l < 16) {
        size_t base = (size_t)sidx * NN;
        pden[(base + ia)*2 + 0] = dsa0;
        pden[(base + ia)*2 + 1] = dsa1;
        pden[(base + ib)*2 + 0] = dsb0;
        pden[(base + ib)*2 + 1] = dsb1;
    }
    size_t pb_ = (size_t)sidx * NN * 256;
#pragma unroll
    for (int r = 0; r < 4; ++r) {
        int rr = kq * 4 + r;
#pragma unroll
        for (int ct = 0; ct < 16; ++ct) {
            pacc[pb_ + (size_t)(i0 + rr)*256 + ct*16 + m]      = f2bf(acc[0][ct][r]);
            pacc[pb_ + (size_t)(i0 + 16 + rr)*256 + ct*16 + m] = f2bf(acc[1][ct][r]);
        }
    }
}

// combine: 8 outputs per thread (uint4 = 8 bf16 per partial)
__global__ void combine_kernel(const unsigned short* __restrict__ pacc, const float* __restrict__ pden,
                               float* __restrict__ out, int S) {
    size_t idx = ((size_t)blockIdx.x * 256 + threadIdx.x) * 8;
    int i = (int)(idx >> 8);
    int c = (int)(idx & 255);
    int hh = c >> 7;
    float acc[8];
#pragma unroll
    for (int e = 0; e < 8; ++e) acc[e] = 0.f;
    float den = 0.f;
    for (int s = 0; s < S; ++s) {
        uint4 v = *(const uint4*)&pacc[(size_t)s * NN * 256 + idx];
        unsigned int uu[4] = {v.x, v.y, v.z, v.w};
#pragma unroll
        for (int q = 0; q < 4; ++q) {
            acc[2*q]   += bf2f((unsigned short)(uu[q] & 0xffff));
            acc[2*q+1] += bf2f((unsigned short)(uu[q] >> 16));
        }
        den += pden[((size_t)s * NN + i) * 2 + hh];
    }
    float r = 1.f / den;
    float4 o0 = {acc[0]*r, acc[1]*r, acc[2]*r, acc[3]*r};
    float4 o1 = {acc[4]*r, acc[5]*r, acc[6]*r, acc[7]*r};
    *(float4*)&out[idx] = o0;
    *(float4*)&out[idx + 4] = o1;
}

extern "C" void kernel_launch(void* const* d_in, const int* in_sizes, int n_in,
                              void* d_out, int out_size, void* d_ws, size_t ws_size,
                              hipStream_t stream) {
    const float* hmat = (const float*)d_in[0];
    const int*   adj  = (const int*)d_in[1];
    const float* W1   = (const float*)d_in[2];
    const float* b1   = (const float*)d_in[3];
    const float* W2   = (const float*)d_in[4];
    const float* b2   = (const float*)d_in[5];
    const float* W3   = (const float*)d_in[6];
    const float* b3   = (const float*)d_in[7];
    const float* a    = (const float*)d_in[8];
    float* out = (float*)d_out;

    char* p = (char*)d_ws;
    float* v1  = (float*)p; p += 2048;
    float* v2  = (float*)p; p += 2048;
    float* bd  = (float*)p; p += 256;
    float* s1  = (float*)p; p += (size_t)NN * 2 * sizeof(float);
    float* s2  = (float*)p; p += (size_t)NN * 2 * sizeof(float);
    float* v1p = (float*)p; p += 8 * 512 * sizeof(float);
    float* v2p = (float*)p; p += 8 * 512 * sizeof(float);
    unsigned short* w3t = (unsigned short*)p; p += (size_t)NN * 256 * 2;
    size_t fixed = (size_t)(p - (char*)d_ws);
    size_t perS = (size_t)NN * 256 * 2 /*pacc bf16*/ + (size_t)NN * 2 * 4 /*pden f32*/;
    int S = 8;                           // ws proven >= 139 MB (round-2/3 ladder evidence)
    if (fixed + 16 * perS <= ws_size) S = 16;
    float* pden = (float*)p; p += (size_t)S * NN * 2 * sizeof(float);
    unsigned short* pacc = (unsigned short*)p;

    prep_partial<<<16, 512, 0, stream>>>(W1, W2, a, v1p, v2p);
    prep_reduce<<<1, 512, 0, stream>>>(b1, b2, a, v1p, v2p, v1, v2, bd);
    s_kernel<<<NN / 4, 256, 0, stream>>>(hmat, v1, v2, bd, s1, s2);
    w3_kernel<<<NN / 32, 128, 0, stream>>>(hmat, W3, b3, w3t);
    int jc = NN / S;
    attn_main<<<dim3(NN / 128, S), 256, 0, stream>>>(adj, s1, s2, w3t, pacc, pden, jc);
    combine_kernel<<<(NN * 256) / (256 * 8), 256, 0, stream>>>(pacc, pden, out, S);
}

// Round 5
// 247.816 us; speedup vs baseline: 1.1243x; 1.1243x over previous
//
#include <hip/hip_runtime.h>
#include <hip/hip_bf16.h>

#define NN 8192
#define LOG2E 1.44269504088896f

typedef __attribute__((ext_vector_type(8))) short short8;
typedef __attribute__((ext_vector_type(4))) float f32x4;

static __device__ __forceinline__ float bf2f(unsigned short u) {
    union { unsigned int i; float f; } v; v.i = ((unsigned int)u) << 16; return v.f;
}
static __device__ __forceinline__ unsigned short f2bf(float f) {
    union { float f; unsigned int i; } v; v.f = f;
    unsigned int lsb = (v.i >> 16) & 1u;
    v.i += 0x7fffu + lsb;
    return (unsigned short)(v.i >> 16);
}
// pack 2 f32 -> 2 bf16 in one u32 (RTNE): low addr gets first arg
static __device__ __forceinline__ unsigned int cvtpk(float lo, float hi) {
    unsigned int r;
    asm("v_cvt_pk_bf16_f32 %0, %1, %2" : "=v"(r) : "v"(lo), "v"(hi));
    return r;
}
static __device__ __forceinline__ float fexp2(float x) { return __builtin_amdgcn_exp2f(x); }

// Convert 8 contiguous f32 to bf16 hi + bf16 residual lo (for split-MFMA).
static __device__ __forceinline__ void cvt8(const float* __restrict__ p, short8& hi, short8& lo) {
    float4 u = *(const float4*)p;
    float4 v = *(const float4*)(p + 4);
    float f[8] = {u.x, u.y, u.z, u.w, v.x, v.y, v.z, v.w};
#pragma unroll
    for (int j = 0; j < 8; ++j) {
        unsigned short hb = f2bf(f[j]);
        hi[j] = (short)hb;
        lo[j] = (short)f2bf(f[j] - bf2f(hb));
    }
}

// ---- prep: v1/v2 (W^T a vectors), split over 16 blocks then reduced ----
__global__ void prep_partial(const float* __restrict__ W1, const float* __restrict__ W2,
                             const float* __restrict__ a,
                             float* __restrict__ v1p, float* __restrict__ v2p) {
    int b = blockIdx.x;            // 0..15
    int t = threadIdx.x;           // 512: (hh, k)
    int hh = t >> 8, k = t & 255;
    int c0 = (b & 7) * 16;
    const float* W = (b < 8) ? W1 : W2;
    int aoff = (b < 8) ? 0 : 128;
    float acc = 0.f;
    for (int c = c0; c < c0 + 16; ++c)
        acc += W[(size_t)(hh * 128 + c) * 256 + k] * a[hh * 256 + aoff + c];
    ((b < 8) ? v1p : v2p)[(b & 7) * 512 + t] = acc;
}

__global__ void prep_reduce(const float* __restrict__ b1, const float* __restrict__ b2,
                            const float* __restrict__ a,
                            const float* __restrict__ v1p, const float* __restrict__ v2p,
                            float* __restrict__ v1, float* __restrict__ v2, float* __restrict__ bd) {
    int t = threadIdx.x;           // 512
    float a1 = 0.f, a2 = 0.f;
    for (int b = 0; b < 8; ++b) { a1 += v1p[b * 512 + t]; a2 += v2p[b * 512 + t]; }
    v1[t] = a1;
    v2[t] = a2;
    if (t < 4) {
        int hh = t >> 1, which = t & 1;
        float d = 0.f;
        for (int c = 0; c < 128; ++c)
            d += which ? b2[hh * 128 + c] * a[hh * 256 + 128 + c]
                       : b1[hh * 128 + c] * a[hh * 256 + c];
        bd[hh * 2 + which] = d;
    }
}

// s1[n][h], s2[n][h] f32, interleaved pairs, PRE-SCALED by log2(e) for exp2-domain P-gen.
__global__ __launch_bounds__(256) void s_kernel(const float* __restrict__ hmat,
                         const float* __restrict__ v1, const float* __restrict__ v2,
                         const float* __restrict__ bd,
                         float* __restrict__ s1o, float* __restrict__ s2o) {
    int w = threadIdx.x >> 6, l = threadIdx.x & 63;
    int n = blockIdx.x * 4 + w;
    float4 hv  = *(const float4*)(hmat + (size_t)n * 256 + l * 4);
    float4 va0 = *(const float4*)(v1 + l * 4);
    float4 va1 = *(const float4*)(v1 + 256 + l * 4);
    float4 vb0 = *(const float4*)(v2 + l * 4);
    float4 vb1 = *(const float4*)(v2 + 256 + l * 4);
    float s10 = hv.x*va0.x + hv.y*va0.y + hv.z*va0.z + hv.w*va0.w;
    float s11 = hv.x*va1.x + hv.y*va1.y + hv.z*va1.z + hv.w*va1.w;
    float s20 = hv.x*vb0.x + hv.y*vb0.y + hv.z*vb0.z + hv.w*vb0.w;
    float s21 = hv.x*vb1.x + hv.y*vb1.y + hv.z*vb1.z + hv.w*vb1.w;
#pragma unroll
    for (int off = 1; off < 64; off <<= 1) {
        s10 += __shfl_xor(s10, off);
        s11 += __shfl_xor(s11, off);
        s20 += __shfl_xor(s20, off);
        s21 += __shfl_xor(s21, off);
    }
    if (l == 0) {
        s1o[n*2 + 0] = (s10 + bd[0]) * LOG2E;
        s1o[n*2 + 1] = (s11 + bd[2]) * LOG2E;
        s2o[n*2 + 0] = (s20 + bd[1]) * LOG2E;
        s2o[n*2 + 1] = (s21 + bd[3]) * LOG2E;
    }
}

// W3hT[c][n] bf16, split-bf16 3-MFMA for ~f32 accuracy.
__global__ __launch_bounds__(128) void w3_kernel(const float* __restrict__ hmat,
                                                 const float* __restrict__ W3,
                                                 const float* __restrict__ b3,
                                                 unsigned short* __restrict__ w3t) {
    int tid = threadIdx.x;
    int w = tid >> 6, l = tid & 63;
    int m = l & 15, kq = l >> 4;
    int n0 = blockIdx.x * 32 + w * 16;
    f32x4 acc[16];
#pragma unroll
    for (int ct = 0; ct < 16; ++ct) acc[ct] = (f32x4){0.f, 0.f, 0.f, 0.f};
    for (int k0 = 0; k0 < 256; k0 += 32) {
        short8 ahi, alo;
        cvt8(hmat + (size_t)(n0 + m) * 256 + k0 + kq * 8, ahi, alo);
#pragma unroll
        for (int ct = 0; ct < 16; ++ct) {
            short8 bhi, blo;
            cvt8(W3 + (size_t)(ct * 16 + m) * 256 + k0 + kq * 8, bhi, blo);
            acc[ct] = __builtin_amdgcn_mfma_f32_16x16x32_bf16(ahi, bhi, acc[ct], 0, 0, 0);
            acc[ct] = __builtin_amdgcn_mfma_f32_16x16x32_bf16(alo, bhi, acc[ct], 0, 0, 0);
            acc[ct] = __builtin_amdgcn_mfma_f32_16x16x32_bf16(ahi, blo, acc[ct], 0, 0, 0);
        }
    }
#pragma unroll
    for (int ct = 0; ct < 16; ++ct) {
        int c = ct * 16 + m;
        float bias = b3[c];
#pragma unroll
        for (int r = 0; r < 4; ++r) {
            int nn = n0 + kq * 4 + r;
            w3t[(size_t)c * NN + nn] = f2bf(acc[ct][r] + bias);
        }
    }
}

// ---- main fused attention ----
// 512 threads = 8 waves. Block = 64 rows x 256 cols; waves: rg = w&1 (rows 32), cg = w>>1
// (cols 64). P (64x32x2h bf16, 8KB) computed cooperatively (8 exps/thread/iter), shared via
// LDS. All LDS layouts linear & conflict-free by granule arithmetic (no swizzles). Two raw
// barriers/iter; counted vmcnt(1) keeps next adj in flight; stage spans a full P-phase.
__global__ __launch_bounds__(512, 4) void attn_fused(
        const int* __restrict__ adj, const float* __restrict__ s1a,
        const float* __restrict__ s2a, const unsigned short* __restrict__ w3t,
        unsigned short* __restrict__ pacc, float* __restrict__ pden, int jc)
{
    __shared__ unsigned short Pt[2][64][32];  // 8 KB [head][row][j]
    __shared__ uint4 Bt[2][1024];             // 2 x 16 KB B-tile [c 256][j 32] bf16
    __shared__ float s2t[2048];               // s2 chunk (jc<=1024)

    const int tid = threadIdx.x;
    const int wv = tid >> 6, ln = tid & 63;
    const int m = ln & 15, kq = ln >> 4;
    const int rg = wv & 1, cg = wv >> 1;     // row-group (32 rows), col-group (64 cols)
    const int hw = cg >> 1;                  // head of this wave's columns
    const int r  = tid >> 3;                 // P-gen row 0..63
    const int oct = tid & 7;                 // P-gen j-quad (4 j)
    const int i0 = blockIdx.x * 64;
    const int sidx = blockIdx.y;
    const int j0 = sidx * jc;
    const int nt = jc >> 5;

    const float s1r0 = s1a[(i0 + r) * 2 + 0];
    const float s1r1 = s1a[(i0 + r) * 2 + 1];
    const int* adjR = adj + (size_t)(i0 + r) * NN + j0 + oct * 4;

    auto stageB = [&](int bsel, int jcol) {
#pragma unroll
        for (int it = 0; it < 2; ++it) {
            int g = tid + it * 512;          // 0..1023 granules of 16B
            int c = g >> 2, js = g & 3;
            const unsigned short* src = w3t + (size_t)c * NN + jcol + js * 8;
            __builtin_amdgcn_global_load_lds(
                (const __attribute__((address_space(1))) void*)src,
                (__attribute__((address_space(3))) void*)((char*)&Bt[bsel][0] + g * 16),
                16, 0, 0);
        }
    };

    f32x4 acc[2][4];
#pragma unroll
    for (int rt = 0; rt < 2; ++rt)
#pragma unroll
        for (int ct = 0; ct < 4; ++ct) acc[rt][ct] = (f32x4){0.f, 0.f, 0.f, 0.f};
    float d0 = 0.f, d1 = 0.f;                // per-thread den partials (4 j, both heads)

    // prologue
    for (int x = tid; x < jc * 2; x += 512) s2t[x] = s2a[j0 * 2 + x];
    stageB(0, j0);
    int4 aE = *(const int4*)(adjR);          // tile 0
    int4 aO = *(const int4*)(adjR + 32);     // tile 1
    __syncthreads();                          // full drain once: publishes s2t + Bt[0]

    auto pgen = [&](int jt, int4 aj4) {
        int aj[4] = {aj4.x, aj4.y, aj4.z, aj4.w};
        float4 sA = *(const float4*)&s2t[2 * (jt + oct * 4)];
        float4 sB = *(const float4*)&s2t[2 * (jt + oct * 4) + 4];
        // pairs: (x,y)=j+0 h0/h1, (z,w)=j+1 h0/h1, etc.
        float t0, t1, q0, q1, q2, q3, u0, u1, u2, u3;
        t0 = s1r0 + sA.x; t0 = fmaxf(t0, 0.2f * t0);
        t1 = s1r0 + sA.z; t1 = fmaxf(t1, 0.2f * t1);
        q0 = aj[0] ? fexp2(t0) : 0.f;
        q1 = aj[1] ? fexp2(t1) : 0.f;
        t0 = s1r0 + sB.x; t0 = fmaxf(t0, 0.2f * t0);
        t1 = s1r0 + sB.z; t1 = fmaxf(t1, 0.2f * t1);
        q2 = aj[2] ? fexp2(t0) : 0.f;
        q3 = aj[3] ? fexp2(t1) : 0.f;
        t0 = s1r1 + sA.y; t0 = fmaxf(t0, 0.2f * t0);
        t1 = s1r1 + sA.w; t1 = fmaxf(t1, 0.2f * t1);
        u0 = aj[0] ? fexp2(t0) : 0.f;
        u1 = aj[1] ? fexp2(t1) : 0.f;
        t0 = s1r1 + sB.y; t0 = fmaxf(t0, 0.2f * t0);
        t1 = s1r1 + sB.w; t1 = fmaxf(t1, 0.2f * t1);
        u2 = aj[2] ? fexp2(t0) : 0.f;
        u3 = aj[3] ? fexp2(t1) : 0.f;
        d0 += (q0 + q1) + (q2 + q3);
        d1 += (u0 + u1) + (u2 + u3);
        uint2 w0 = {cvtpk(q0, q1), cvtpk(q2, q3)};
        uint2 w1 = {cvtpk(u0, u1), cvtpk(u2, u3)};
        *(uint2*)&Pt[0][r][oct * 4] = w0;
        *(uint2*)&Pt[1][r][oct * 4] = w1;
    };

    auto mfma_phase = [&](int cur, int nxt, int tnext) {
        stageB(nxt, j0 + tnext * 32);
        const unsigned short* B = (const unsigned short*)&Bt[cur][0];
        short8 a0 = *(const short8*)&Pt[hw][rg * 32 + m][kq * 8];
        short8 a1 = *(const short8*)&Pt[hw][rg * 32 + 16 + m][kq * 8];
#pragma unroll
        for (int ct = 0; ct < 4; ++ct) {
            int c = cg * 64 + ct * 16 + m;
            short8 bf = *(const short8*)&B[c * 32 + kq * 8];
            acc[0][ct] = __builtin_amdgcn_mfma_f32_16x16x32_bf16(a0, bf, acc[0][ct], 0, 0, 0);
            acc[1][ct] = __builtin_amdgcn_mfma_f32_16x16x32_bf16(a1, bf, acc[1][ct], 0, 0, 0);
        }
    };

    for (int t = 0; t < nt; t += 2) {
        // ---- even iter: P for tile t, MFMA on Bt[0], stage into Bt[1] ----
        {
            int4 cur = aE;
            int nx = (t + 2 < nt) ? t + 2 : nt - 1;
            aE = *(const int4*)(adjR + nx * 32);
            pgen(t * 32, cur);
            asm volatile("s_waitcnt lgkmcnt(0) vmcnt(1)" ::: "memory");
            __builtin_amdgcn_s_barrier();
            asm volatile("" ::: "memory");
            int tn = (t + 1 < nt) ? t + 1 : nt - 1;
            mfma_phase(0, 1, tn);
            asm volatile("" ::: "memory");
            __builtin_amdgcn_s_barrier();
            asm volatile("" ::: "memory");
        }
        // ---- odd iter: P for tile t+1, MFMA on Bt[1], stage into Bt[0] ----
        {
            int4 cur = aO;
            int nx = (t + 3 < nt) ? t + 3 : nt - 1;
            aO = *(const int4*)(adjR + nx * 32);
            pgen((t + 1) * 32, cur);
            asm volatile("s_waitcnt lgkmcnt(0) vmcnt(1)" ::: "memory");
            __builtin_amdgcn_s_barrier();
            asm volatile("" ::: "memory");
            int tn = (t + 2 < nt) ? t + 2 : nt - 1;
            mfma_phase(1, 0, tn);
            asm volatile("" ::: "memory");
            __builtin_amdgcn_s_barrier();
            asm volatile("" ::: "memory");
        }
    }

    // den: reduce over the 8 j-quad threads of each row (low 3 lane bits)
    d0 += __shfl_xor(d0, 1); d0 += __shfl_xor(d0, 2); d0 += __shfl_xor(d0, 4);
    d1 += __shfl_xor(d1, 1); d1 += __shfl_xor(d1, 2); d1 += __shfl_xor(d1, 4);
    if (oct == 0) {
        size_t base = ((size_t)sidx * NN + i0 + r) * 2;
        pden[base + 0] = d0;
        pden[base + 1] = d1;
    }
    // pacc
    size_t pb_ = (size_t)sidx * NN * 256;
#pragma unroll
    for (int rt = 0; rt < 2; ++rt)
#pragma unroll
        for (int reg = 0; reg < 4; ++reg) {
            int row = i0 + rg * 32 + rt * 16 + kq * 4 + reg;
#pragma unroll
            for (int ct = 0; ct < 4; ++ct) {
                int col = cg * 64 + ct * 16 + m;
                pacc[pb_ + (size_t)row * 256 + col] = f2bf(acc[rt][ct][reg]);
            }
        }
}

// combine: 8 outputs per thread (uint4 = 8 bf16 per partial)
__global__ void combine_kernel(const unsigned short* __restrict__ pacc, const float* __restrict__ pden,
                               float* __restrict__ out, int S) {
    size_t idx = ((size_t)blockIdx.x * 256 + threadIdx.x) * 8;
    int i = (int)(idx >> 8);
    int c = (int)(idx & 255);
    int hh = c >> 7;
    float acc[8];
#pragma unroll
    for (int e = 0; e < 8; ++e) acc[e] = 0.f;
    float den = 0.f;
    for (int s = 0; s < S; ++s) {
        uint4 v = *(const uint4*)&pacc[(size_t)s * NN * 256 + idx];
        unsigned int uu[4] = {v.x, v.y, v.z, v.w};
#pragma unroll
        for (int q = 0; q < 4; ++q) {
            acc[2*q]   += bf2f((unsigned short)(uu[q] & 0xffff));
            acc[2*q+1] += bf2f((unsigned short)(uu[q] >> 16));
        }
        den += pden[((size_t)s * NN + i) * 2 + hh];
    }
    float r = 1.f / den;
    float4 o0 = {acc[0]*r, acc[1]*r, acc[2]*r, acc[3]*r};
    float4 o1 = {acc[4]*r, acc[5]*r, acc[6]*r, acc[7]*r};
    *(float4*)&out[idx] = o0;
    *(float4*)&out[idx + 4] = o1;
}

extern "C" void kernel_launch(void* const* d_in, const int* in_sizes, int n_in,
                              void* d_out, int out_size, void* d_ws, size_t ws_size,
                              hipStream_t stream) {
    const float* hmat = (const float*)d_in[0];
    const int*   adj  = (const int*)d_in[1];
    const float* W1   = (const float*)d_in[2];
    const float* b1   = (const float*)d_in[3];
    const float* W2   = (const float*)d_in[4];
    const float* b2   = (const float*)d_in[5];
    const float* W3   = (const float*)d_in[6];
    const float* b3   = (const float*)d_in[7];
    const float* a    = (const float*)d_in[8];
    float* out = (float*)d_out;

    char* p = (char*)d_ws;
    float* v1  = (float*)p; p += 2048;
    float* v2  = (float*)p; p += 2048;
    float* bd  = (float*)p; p += 256;
    float* s1  = (float*)p; p += (size_t)NN * 2 * sizeof(float);
    float* s2  = (float*)p; p += (size_t)NN * 2 * sizeof(float);
    float* v1p = (float*)p; p += 8 * 512 * sizeof(float);
    float* v2p = (float*)p; p += 8 * 512 * sizeof(float);
    unsigned short* w3t = (unsigned short*)p; p += (size_t)NN * 256 * 2;
    size_t fixed = (size_t)(p - (char*)d_ws);
    size_t perS = (size_t)NN * 256 * 2 /*pacc bf16*/ + (size_t)NN * 2 * 4 /*pden f32*/;
    int S = 8;
    if (fixed + 16 * perS <= ws_size) S = 16;   // ws observed ~1.07 GB (fill counter) -> fits
    float* pden = (float*)p; p += (size_t)S * NN * 2 * sizeof(float);
    unsigned short* pacc = (unsigned short*)p;

    prep_partial<<<16, 512, 0, stream>>>(W1, W2, a, v1p, v2p);
    prep_reduce<<<1, 512, 0, stream>>>(b1, b2, a, v1p, v2p, v1, v2, bd);
    s_kernel<<<NN / 4, 256, 0, stream>>>(hmat, v1, v2, bd, s1, s2);
    w3_kernel<<<NN / 32, 128, 0, stream>>>(hmat, W3, b3, w3t);
    int jc = NN / S;
    attn_fused<<<dim3(NN / 64, S), 512, 0, stream>>>(adj, s1, s2, w3t, pacc, pden, jc);
    combine_kernel<<<(NN * 256) / (256 * 8), 256, 0, stream>>>(pacc, pden, out, S);
}

// Round 6
// 235.847 us; speedup vs baseline: 1.1813x; 1.0508x over previous
//
#include <hip/hip_runtime.h>
#include <hip/hip_bf16.h>

#define NN 8192
#define LOG2E 1.44269504088896f

typedef __attribute__((ext_vector_type(8))) short short8;
typedef __attribute__((ext_vector_type(4))) float f32x4;

static __device__ __forceinline__ float bf2f(unsigned short u) {
    union { unsigned int i; float f; } v; v.i = ((unsigned int)u) << 16; return v.f;
}
static __device__ __forceinline__ unsigned short f2bf(float f) {
    union { float f; unsigned int i; } v; v.f = f;
    unsigned int lsb = (v.i >> 16) & 1u;
    v.i += 0x7fffu + lsb;
    return (unsigned short)(v.i >> 16);
}
static __device__ __forceinline__ unsigned int cvtpk(float lo, float hi) {
    unsigned int r;
    asm("v_cvt_pk_bf16_f32 %0, %1, %2" : "=v"(r) : "v"(lo), "v"(hi));
    return r;
}
static __device__ __forceinline__ float fexp2(float x) { return __builtin_amdgcn_exp2f(x); }

static __device__ __forceinline__ void cvt8(const float* __restrict__ p, short8& hi, short8& lo) {
    float4 u = *(const float4*)p;
    float4 v = *(const float4*)(p + 4);
    float f[8] = {u.x, u.y, u.z, u.w, v.x, v.y, v.z, v.w};
#pragma unroll
    for (int j = 0; j < 8; ++j) {
        unsigned short hb = f2bf(f[j]);
        hi[j] = (short)hb;
        lo[j] = (short)f2bf(f[j] - bf2f(hb));
    }
}

// ---- prep: v1/v2 (W^T a vectors), split over 16 blocks then reduced ----
__global__ void prep_partial(const float* __restrict__ W1, const float* __restrict__ W2,
                             const float* __restrict__ a,
                             float* __restrict__ v1p, float* __restrict__ v2p) {
    int b = blockIdx.x;
    int t = threadIdx.x;
    int hh = t >> 8, k = t & 255;
    int c0 = (b & 7) * 16;
    const float* W = (b < 8) ? W1 : W2;
    int aoff = (b < 8) ? 0 : 128;
    float acc = 0.f;
    for (int c = c0; c < c0 + 16; ++c)
        acc += W[(size_t)(hh * 128 + c) * 256 + k] * a[hh * 256 + aoff + c];
    ((b < 8) ? v1p : v2p)[(b & 7) * 512 + t] = acc;
}

__global__ void prep_reduce(const float* __restrict__ b1, const float* __restrict__ b2,
                            const float* __restrict__ a,
                            const float* __restrict__ v1p, const float* __restrict__ v2p,
                            float* __restrict__ v1, float* __restrict__ v2, float* __restrict__ bd) {
    int t = threadIdx.x;
    float a1 = 0.f, a2 = 0.f;
    for (int b = 0; b < 8; ++b) { a1 += v1p[b * 512 + t]; a2 += v2p[b * 512 + t]; }
    v1[t] = a1;
    v2[t] = a2;
    if (t < 4) {
        int hh = t >> 1, which = t & 1;
        float d = 0.f;
        for (int c = 0; c < 128; ++c)
            d += which ? b2[hh * 128 + c] * a[hh * 256 + 128 + c]
                       : b1[hh * 128 + c] * a[hh * 256 + c];
        bd[hh * 2 + which] = d;
    }
}

// s1[n][h], s2[n][h] f32 interleaved, pre-scaled by log2(e).
__global__ __launch_bounds__(256) void s_kernel(const float* __restrict__ hmat,
                         const float* __restrict__ v1, const float* __restrict__ v2,
                         const float* __restrict__ bd,
                         float* __restrict__ s1o, float* __restrict__ s2o) {
    int w = threadIdx.x >> 6, l = threadIdx.x & 63;
    int n = blockIdx.x * 4 + w;
    float4 hv  = *(const float4*)(hmat + (size_t)n * 256 + l * 4);
    float4 va0 = *(const float4*)(v1 + l * 4);
    float4 va1 = *(const float4*)(v1 + 256 + l * 4);
    float4 vb0 = *(const float4*)(v2 + l * 4);
    float4 vb1 = *(const float4*)(v2 + 256 + l * 4);
    float s10 = hv.x*va0.x + hv.y*va0.y + hv.z*va0.z + hv.w*va0.w;
    float s11 = hv.x*va1.x + hv.y*va1.y + hv.z*va1.z + hv.w*va1.w;
    float s20 = hv.x*vb0.x + hv.y*vb0.y + hv.z*vb0.z + hv.w*vb0.w;
    float s21 = hv.x*vb1.x + hv.y*vb1.y + hv.z*vb1.z + hv.w*vb1.w;
#pragma unroll
    for (int off = 1; off < 64; off <<= 1) {
        s10 += __shfl_xor(s10, off);
        s11 += __shfl_xor(s11, off);
        s20 += __shfl_xor(s20, off);
        s21 += __shfl_xor(s21, off);
    }
    if (l == 0) {
        s1o[n*2 + 0] = (s10 + bd[0]) * LOG2E;
        s1o[n*2 + 1] = (s11 + bd[2]) * LOG2E;
        s2o[n*2 + 0] = (s20 + bd[1]) * LOG2E;
        s2o[n*2 + 1] = (s21 + bd[3]) * LOG2E;
    }
}

// W3hT[c][n] bf16, split-bf16 3-MFMA.
__global__ __launch_bounds__(128) void w3_kernel(const float* __restrict__ hmat,
                                                 const float* __restrict__ W3,
                                                 const float* __restrict__ b3,
                                                 unsigned short* __restrict__ w3t) {
    int tid = threadIdx.x;
    int w = tid >> 6, l = tid & 63;
    int m = l & 15, kq = l >> 4;
    int n0 = blockIdx.x * 32 + w * 16;
    f32x4 acc[16];
#pragma unroll
    for (int ct = 0; ct < 16; ++ct) acc[ct] = (f32x4){0.f, 0.f, 0.f, 0.f};
    for (int k0 = 0; k0 < 256; k0 += 32) {
        short8 ahi, alo;
        cvt8(hmat + (size_t)(n0 + m) * 256 + k0 + kq * 8, ahi, alo);
#pragma unroll
        for (int ct = 0; ct < 16; ++ct) {
            short8 bhi, blo;
            cvt8(W3 + (size_t)(ct * 16 + m) * 256 + k0 + kq * 8, bhi, blo);
            acc[ct] = __builtin_amdgcn_mfma_f32_16x16x32_bf16(ahi, bhi, acc[ct], 0, 0, 0);
            acc[ct] = __builtin_amdgcn_mfma_f32_16x16x32_bf16(alo, bhi, acc[ct], 0, 0, 0);
            acc[ct] = __builtin_amdgcn_mfma_f32_16x16x32_bf16(ahi, blo, acc[ct], 0, 0, 0);
        }
    }
#pragma unroll
    for (int ct = 0; ct < 16; ++ct) {
        int c = ct * 16 + m;
        float bias = b3[c];
#pragma unroll
        for (int r = 0; r < 4; ++r) {
            int nn = n0 + kq * 4 + r;
            w3t[(size_t)c * NN + nn] = f2bf(acc[ct][r] + bias);
        }
    }
}

// ---- main fused attention ----
// 512 threads = 8 waves; block = 64 rows x 256 cols (wave: 32r x 64c). XOR granule swizzle
// (g ^= (row>>1)&3) on Bt (pre-swizzled global source, linear LDS dest) and Pt (swizzled
// write+read) => every consecutive 8-lane group of a ds_read_b128 covers all 8 bank-groups
// (round-4 measured-zero pattern). 3 blocks/CU: LDS 48KB, launch_bounds(512,6).
// Counted vmcnt(1): only the adj prefetch crosses the barrier.
__global__ __launch_bounds__(512, 6) void attn_fused(
        const int* __restrict__ adj, const float* __restrict__ s1a,
        const float* __restrict__ s2a, const unsigned short* __restrict__ w3t,
        unsigned short* __restrict__ pacc, float* __restrict__ pden, int jc)
{
    __shared__ unsigned short Pt[2][64][32];  // 8 KB, swizzled granules
    __shared__ uint4 Bt[2][1024];             // 2 x 16 KB, [c 256][j 32]
    __shared__ float s2t[2048];               // s2 chunk (jc<=1024)

    const int tid = threadIdx.x;
    const int wv = tid >> 6, ln = tid & 63;
    const int m = ln & 15, kq = ln >> 4;
    const int rg = wv & 1, cg = wv >> 1;
    const int hw = cg >> 1;
    const int r  = tid >> 3;
    const int oct = tid & 7;
    const int i0 = blockIdx.x * 64;
    const int sidx = blockIdx.y;
    const int j0 = sidx * jc;
    const int nt = jc >> 5;
    const int sw = kq ^ ((m >> 1) & 3);       // read-side swizzled granule

    const float s1r0 = s1a[(i0 + r) * 2 + 0];
    const float s1r1 = s1a[(i0 + r) * 2 + 1];
    const int* adjR = adj + (size_t)(i0 + r) * NN + j0 + oct * 4;

    // swizzled Pt write pointer (uint2 half-granule)
    unsigned short* ptw = &Pt[0][0][0] + r * 32 + ((((oct >> 1) ^ ((r >> 1) & 3)) << 3) | ((oct & 1) << 2));
    // swizzled Pt read pointer (b128 granule)
    const unsigned short* pta = &Pt[hw][rg * 32 + m][0] + (sw << 3);
    // swizzled Bt read base (row cg*64+m, ct adds 16 rows = 1024B)
    const int btoff = (cg * 64 + m) * 64 + (sw << 4);

    auto stageB = [&](int bsel, int jcol) {
#pragma unroll
        for (int it2 = 0; it2 < 2; ++it2) {
            int g = tid + it2 * 512;          // 0..1023
            int c = g >> 2, js = g & 3;
            const unsigned short* src = w3t + (size_t)c * NN + jcol + ((js ^ ((c >> 1) & 3)) << 3);
            __builtin_amdgcn_global_load_lds(
                (const __attribute__((address_space(1))) void*)src,
                (__attribute__((address_space(3))) void*)((char*)&Bt[bsel][0] + g * 16),
                16, 0, 0);
        }
    };

    f32x4 acc[2][4];
#pragma unroll
    for (int rt = 0; rt < 2; ++rt)
#pragma unroll
        for (int ct = 0; ct < 4; ++ct) acc[rt][ct] = (f32x4){0.f, 0.f, 0.f, 0.f};
    float d0 = 0.f, d1 = 0.f;

    // prologue: s2 chunk -> LDS, stage tile 0, adj tile 0; one full drain
    for (int x = tid; x < jc * 2; x += 512) s2t[x] = s2a[j0 * 2 + x];
    stageB(0, j0);
    int4 aC = *(const int4*)(adjR);
    __syncthreads();

    for (int t = 0; t < nt; ++t) {
        const int cur = t & 1;
        const int jt = t * 32;
        const int tp = (t + 1 < nt) ? t + 1 : nt - 1;
        // ---- P-gen(t) from regs + LDS s2 ----
        {
            int aj[4] = {aC.x, aC.y, aC.z, aC.w};
            float4 sA = *(const float4*)&s2t[2 * (jt + oct * 4)];
            float4 sB = *(const float4*)&s2t[2 * (jt + oct * 4) + 4];
            float t0, t1, q0, q1, q2, q3, u0, u1, u2, u3;
            t0 = s1r0 + sA.x; t0 = fmaxf(t0, 0.2f * t0);
            t1 = s1r0 + sA.z; t1 = fmaxf(t1, 0.2f * t1);
            q0 = aj[0] ? fexp2(t0) : 0.f;
            q1 = aj[1] ? fexp2(t1) : 0.f;
            t0 = s1r0 + sB.x; t0 = fmaxf(t0, 0.2f * t0);
            t1 = s1r0 + sB.z; t1 = fmaxf(t1, 0.2f * t1);
            q2 = aj[2] ? fexp2(t0) : 0.f;
            q3 = aj[3] ? fexp2(t1) : 0.f;
            t0 = s1r1 + sA.y; t0 = fmaxf(t0, 0.2f * t0);
            t1 = s1r1 + sA.w; t1 = fmaxf(t1, 0.2f * t1);
            u0 = aj[0] ? fexp2(t0) : 0.f;
            u1 = aj[1] ? fexp2(t1) : 0.f;
            t0 = s1r1 + sB.y; t0 = fmaxf(t0, 0.2f * t0);
            t1 = s1r1 + sB.w; t1 = fmaxf(t1, 0.2f * t1);
            u2 = aj[2] ? fexp2(t0) : 0.f;
            u3 = aj[3] ? fexp2(t1) : 0.f;
            d0 += (q0 + q1) + (q2 + q3);
            d1 += (u0 + u1) + (u2 + u3);
            uint2 w0 = {cvtpk(q0, q1), cvtpk(q2, q3)};
            uint2 w1 = {cvtpk(u0, u1), cvtpk(u2, u3)};
            *(uint2*)ptw = w0;
            *(uint2*)(ptw + 2048) = w1;
        }
        // prefetch adj(t+1) — stays in flight across the barrier
        int4 aN = *(const int4*)(adjR + tp * 32);
        asm volatile("s_waitcnt vmcnt(1) lgkmcnt(0)" ::: "memory"); // stage(t) drained (FIFO-oldest)
        __builtin_amdgcn_sched_barrier(0);
        __builtin_amdgcn_s_barrier();
        asm volatile("" ::: "memory");
        // ---- stage(t+1) + MFMA(t) ----
        stageB(cur ^ 1, j0 + tp * 32);
        {
            short8 a0 = *(const short8*)pta;
            short8 a1 = *(const short8*)(pta + 512);
            const char* bb = (const char*)&Bt[cur][0] + btoff;
            __builtin_amdgcn_s_setprio(1);
#pragma unroll
            for (int ct = 0; ct < 4; ++ct) {
                short8 bf = *(const short8*)(bb + ct * 1024);
                acc[0][ct] = __builtin_amdgcn_mfma_f32_16x16x32_bf16(a0, bf, acc[0][ct], 0, 0, 0);
                acc[1][ct] = __builtin_amdgcn_mfma_f32_16x16x32_bf16(a1, bf, acc[1][ct], 0, 0, 0);
            }
            __builtin_amdgcn_s_setprio(0);
        }
        asm volatile("" ::: "memory");
        __builtin_amdgcn_s_barrier();
        asm volatile("" ::: "memory");
        aC = aN;
    }

    d0 += __shfl_xor(d0, 1); d0 += __shfl_xor(d0, 2); d0 += __shfl_xor(d0, 4);
    d1 += __shfl_xor(d1, 1); d1 += __shfl_xor(d1, 2); d1 += __shfl_xor(d1, 4);
    if (oct == 0) {
        size_t base = ((size_t)sidx * NN + i0 + r) * 2;
        pden[base + 0] = d0;
        pden[base + 1] = d1;
    }
    size_t pb_ = (size_t)sidx * NN * 256;
#pragma unroll
    for (int rt = 0; rt < 2; ++rt)
#pragma unroll
        for (int reg = 0; reg < 4; ++reg) {
            int row = i0 + rg * 32 + rt * 16 + kq * 4 + reg;
#pragma unroll
            for (int ct = 0; ct < 4; ++ct) {
                int col = cg * 64 + ct * 16 + m;
                pacc[pb_ + (size_t)row * 256 + col] = f2bf(acc[rt][ct][reg]);
            }
        }
}

// combine: 8 outputs per thread
__global__ void combine_kernel(const unsigned short* __restrict__ pacc, const float* __restrict__ pden,
                               float* __restrict__ out, int S) {
    size_t idx = ((size_t)blockIdx.x * 256 + threadIdx.x) * 8;
    int i = (int)(idx >> 8);
    int c = (int)(idx & 255);
    int hh = c >> 7;
    float acc[8];
#pragma unroll
    for (int e = 0; e < 8; ++e) acc[e] = 0.f;
    float den = 0.f;
    for (int s = 0; s < S; ++s) {
        uint4 v = *(const uint4*)&pacc[(size_t)s * NN * 256 + idx];
        unsigned int uu[4] = {v.x, v.y, v.z, v.w};
#pragma unroll
        for (int q = 0; q < 4; ++q) {
            acc[2*q]   += bf2f((unsigned short)(uu[q] & 0xffff));
            acc[2*q+1] += bf2f((unsigned short)(uu[q] >> 16));
        }
        den += pden[((size_t)s * NN + i) * 2 + hh];
    }
    float r = 1.f / den;
    float4 o0 = {acc[0]*r, acc[1]*r, acc[2]*r, acc[3]*r};
    float4 o1 = {acc[4]*r, acc[5]*r, acc[6]*r, acc[7]*r};
    *(float4*)&out[idx] = o0;
    *(float4*)&out[idx + 4] = o1;
}

extern "C" void kernel_launch(void* const* d_in, const int* in_sizes, int n_in,
                              void* d_out, int out_size, void* d_ws, size_t ws_size,
                              hipStream_t stream) {
    const float* hmat = (const float*)d_in[0];
    const int*   adj  = (const int*)d_in[1];
    const float* W1   = (const float*)d_in[2];
    const float* b1   = (const float*)d_in[3];
    const float* W2   = (const float*)d_in[4];
    const float* b2   = (const float*)d_in[5];
    const float* W3   = (const float*)d_in[6];
    const float* b3   = (const float*)d_in[7];
    const float* a    = (const float*)d_in[8];
    float* out = (float*)d_out;

    char* p = (char*)d_ws;
    float* v1  = (float*)p; p += 2048;
    float* v2  = (float*)p; p += 2048;
    float* bd  = (float*)p; p += 256;
    float* s1  = (float*)p; p += (size_t)NN * 2 * sizeof(float);
    float* s2  = (float*)p; p += (size_t)NN * 2 * sizeof(float);
    float* v1p = (float*)p; p += 8 * 512 * sizeof(float);
    float* v2p = (float*)p; p += 8 * 512 * sizeof(float);
    unsigned short* w3t = (unsigned short*)p; p += (size_t)NN * 256 * 2;
    size_t fixed = (size_t)(p - (char*)d_ws);
    size_t perS = (size_t)NN * 256 * 2 + (size_t)NN * 2 * 4;
    int S = 8;
    if (fixed + 16 * perS <= ws_size) S = 16;
    float* pden = (float*)p; p += (size_t)S * NN * 2 * sizeof(float);
    unsigned short* pacc = (unsigned short*)p;

    prep_partial<<<16, 512, 0, stream>>>(W1, W2, a, v1p, v2p);
    prep_reduce<<<1, 512, 0, stream>>>(b1, b2, a, v1p, v2p, v1, v2, bd);
    s_kernel<<<NN / 4, 256, 0, stream>>>(hmat, v1, v2, bd, s1, s2);
    w3_kernel<<<NN / 32, 128, 0, stream>>>(hmat, W3, b3, w3t);
    int jc = NN / S;
    attn_fused<<<dim3(NN / 64, S), 512, 0, stream>>>(adj, s1, s2, w3t, pacc, pden, jc);
    combine_kernel<<<(NN * 256) / (256 * 8), 256, 0, stream>>>(pacc, pden, out, S);
}